// Round 6
// baseline (1634.137 us; speedup 1.0000x reference)
//
#include <hip/hip_runtime.h>
#include <stdint.h>

typedef __bf16  bf16x8 __attribute__((ext_vector_type(8)));
typedef float   f32x4  __attribute__((ext_vector_type(4)));
typedef unsigned short u16;

#define TEMP 5.0f
#define CNPAD 51072   // 399 tiles of 128

// ---------- helpers ----------
__device__ inline float wsum(float v){
  #pragma unroll
  for (int off=32; off; off>>=1) v += __shfl_xor(v, off, 64);
  return v;
}
__device__ inline float wmax(float v){
  #pragma unroll
  for (int off=32; off; off>>=1) v = fmaxf(v, __shfl_xor(v, off, 64));
  return v;
}
__device__ inline u16 f2bf(float f){               // RNE float->bf16
  unsigned u = __float_as_uint(f);
  u = u + 0x7fffu + ((u>>16)&1u);
  return (u16)(u>>16);
}
__device__ inline float bfl(unsigned u){ return __uint_as_float(u<<16); }
__device__ inline float bfh(unsigned u){ return __uint_as_float(u & 0xffff0000u); }

// async 16B global->LDS: lds dst is WAVE-UNIFORM base, HW adds lane*16
__device__ inline void cp16(void* lds_uniform, const void* g){
  __builtin_amdgcn_global_load_lds(
    (const __attribute__((address_space(1))) unsigned int*)g,
    (__attribute__((address_space(3))) unsigned int*)lds_uniform, 16, 0, 0);
}

// ---------- K0: normalize image features (32x512) ----------
__global__ void k_img(const float* __restrict__ X, float* __restrict__ imgn){
  int b = blockIdx.x, lane = threadIdx.x;
  const float* src = X + (size_t)b*512 + lane*8;
  float4 a = *(const float4*)src;
  float4 c = *(const float4*)(src+4);
  float ss = a.x*a.x+a.y*a.y+a.z*a.z+a.w*a.w + c.x*c.x+c.y*c.y+c.z*c.z+c.w*c.w;
  ss = wsum(ss);
  float inv = 1.0f/sqrtf(ss);
  float* dst = imgn + (size_t)b*512 + lane*8;
  float4 o0 = {a.x*inv,a.y*inv,a.z*inv,a.w*inv};
  float4 o1 = {c.x*inv,c.y*inv,c.z*inv,c.w*inv};
  *(float4*)dst = o0; *(float4*)(dst+4) = o1;
}

// ---------- K1: normalize txt; bf16 K-chunked TXT[kc][cn(51072)][32]; invn[n*1000+c] ----------
__global__ void k_txt(const float* __restrict__ X, u16* __restrict__ TXT, float* __restrict__ invn){
  int cn = blockIdx.x, lane = threadIdx.x;
  int kc = lane>>2, kk8 = (lane&3)*8;
  size_t dstE = ((size_t)kc*CNPAD + cn)*32 + kk8;
  if (cn >= 51000){
    uint4 z = {0,0,0,0};
    *(uint4*)(TXT + dstE) = z;
    return;
  }
  int c = cn/51, n = cn - c*51;
  const float* src = X + ((size_t)n*1000 + c)*512 + lane*8;
  float4 a = *(const float4*)src;
  float4 d = *(const float4*)(src+4);
  float ss = a.x*a.x+a.y*a.y+a.z*a.z+a.w*a.w + d.x*d.x+d.y*d.y+d.z*d.z+d.w*d.w;
  ss = wsum(ss);
  float inv = 1.0f/sqrtf(ss);
  u16 h0=f2bf(a.x*inv),h1=f2bf(a.y*inv),h2=f2bf(a.z*inv),h3=f2bf(a.w*inv);
  u16 h4=f2bf(d.x*inv),h5=f2bf(d.y*inv),h6=f2bf(d.z*inv),h7=f2bf(d.w*inv);
  uint4 o;
  o.x = (unsigned)h0 | ((unsigned)h1<<16);
  o.y = (unsigned)h2 | ((unsigned)h3<<16);
  o.z = (unsigned)h4 | ((unsigned)h5<<16);
  o.w = (unsigned)h6 | ((unsigned)h7<<16);
  *(uint4*)(TXT + dstE) = o;
  if (lane==0) invn[(size_t)n*1000 + c] = inv;
}

// ---------- K2: mean_txt[c] = l2norm( sum_n txt_n[c] ) ----------
__global__ void k_mean(const float* __restrict__ X, const float* __restrict__ invn, float* __restrict__ MT){
  int c = blockIdx.x, tid = threadIdx.x, lane = tid&63, wv = tid>>6;
  __shared__ float sinv[51];
  __shared__ float red[4];
  if (tid < 51) sinv[tid] = invn[(size_t)tid*1000 + c];
  __syncthreads();
  int d0 = tid*2;
  float sx=0.f, sy=0.f;
  for (int n=0;n<51;++n){
    const float2 x = *(const float2*)(X + ((size_t)n*1000 + c)*512 + d0);
    float iv = sinv[n];
    sx += x.x*iv; sy += x.y*iv;
  }
  float ss = sx*sx + sy*sy;
  ss = wsum(ss);
  if (lane==0) red[wv] = ss;
  __syncthreads();
  float tot = red[0]+red[1]+red[2]+red[3];
  float inv = 1.0f/sqrtf(tot);
  float2 o = {sx*inv, sy*inv};
  *(float2*)(MT + (size_t)c*512 + d0) = o;
}

// ---------- K3: v[c,n] = softmax_n( TEMP * mean_txt[c].txt[n,c] ) ----------
__global__ void k_v(const u16* __restrict__ TXT, const float* __restrict__ MT, float* __restrict__ vbuf){
  int c = blockIdx.x, lane = threadIdx.x;
  __shared__ float lg[51];
  const float* mp = MT + (size_t)c*512 + lane*8;
  float4 m0 = *(const float4*)mp;
  float4 m1 = *(const float4*)(mp+4);
  int kc = lane>>2, kk8 = (lane&3)*8;
  for (int n=0;n<51;++n){
    size_t e = ((size_t)kc*CNPAD + (size_t)(c*51+n))*32 + kk8;
    uint4 q = *(const uint4*)(TXT + e);
    float d = bfl(q.x)*m0.x + bfh(q.x)*m0.y + bfl(q.y)*m0.z + bfh(q.y)*m0.w
            + bfl(q.z)*m1.x + bfh(q.z)*m1.y + bfl(q.w)*m1.z + bfh(q.w)*m1.w;
    d = wsum(d);
    if (lane==0) lg[n] = d;
  }
  __syncthreads();
  float val = (lane<51) ? lg[lane] : -1e30f;
  float mx = wmax(val);
  float e = (lane<51) ? expf(TEMP*(val-mx)) : 0.f;
  float s = wsum(e);
  if (lane<51) vbuf[(size_t)c*51 + lane] = e/s;
}

// ---------- K4: bias[b,c] = base_logits ----------
__global__ void k_base(const float* __restrict__ imgn, const float* __restrict__ MT, float* __restrict__ bias){
  int c = blockIdx.x, lane = threadIdx.x;
  const float* mp = MT + (size_t)c*512 + lane*8;
  float4 m0 = *(const float4*)mp;
  float4 m1 = *(const float4*)(mp+4);
  for (int b=0;b<32;++b){
    const float* ip = imgn + (size_t)b*512 + lane*8;
    float4 i0 = *(const float4*)ip;
    float4 i1 = *(const float4*)(ip+4);
    float d = i0.x*m0.x+i0.y*m0.y+i0.z*m0.z+i0.w*m0.w
            + i1.x*m1.x+i1.y*m1.y+i1.z*m1.z+i1.w*m1.w;
    d = wsum(d);
    if (lane==0) bias[(size_t)b*1000 + c] = d;
  }
}

// ---------- K5: normalize loc; LOC[b][kc][m(224)][32] bf16; ew[b,m] ----------
__global__ void k_loc(const float* __restrict__ L, const float* __restrict__ imgn,
                      u16* __restrict__ LOC, float* __restrict__ ewg){
  int m = blockIdx.x, b = blockIdx.y, lane = threadIdx.x;
  size_t dstE = ((size_t)(b*16 + (lane>>2))*224 + m)*32 + (lane&3)*8;
  if (m >= 196){
    uint4 z = {0,0,0,0};
    *(uint4*)(LOC + dstE) = z;
    if (lane==0) ewg[(size_t)b*224 + m] = 0.f;
    return;
  }
  const float* src = L + ((size_t)b*196 + m)*512 + lane*8;
  float4 a = *(const float4*)src;
  float4 d = *(const float4*)(src+4);
  const float* ip = imgn + (size_t)b*512 + lane*8;
  float4 i0 = *(const float4*)ip;
  float4 i1 = *(const float4*)(ip+4);
  float ss = a.x*a.x+a.y*a.y+a.z*a.z+a.w*a.w + d.x*d.x+d.y*d.y+d.z*d.z+d.w*d.w;
  float ws = a.x*i0.x+a.y*i0.y+a.z*i0.z+a.w*i0.w + d.x*i1.x+d.y*i1.y+d.z*i1.z+d.w*i1.w;
  ss = wsum(ss); ws = wsum(ws);
  float inv = 1.0f/sqrtf(ss);
  u16 h0=f2bf(a.x*inv),h1=f2bf(a.y*inv),h2=f2bf(a.z*inv),h3=f2bf(a.w*inv);
  u16 h4=f2bf(d.x*inv),h5=f2bf(d.y*inv),h6=f2bf(d.z*inv),h7=f2bf(d.w*inv);
  uint4 o;
  o.x = (unsigned)h0 | ((unsigned)h1<<16);
  o.y = (unsigned)h2 | ((unsigned)h3<<16);
  o.z = (unsigned)h4 | ((unsigned)h5<<16);
  o.w = (unsigned)h6 | ((unsigned)h7<<16);
  *(uint4*)(LOC + dstE) = o;
  if (lane==0) ewg[(size_t)b*224 + m] = expf(TEMP * ws * inv);
}

// ---------- K6: fused GEMM (MFMA bf16) + top-50 + weighted sum -> atomicAdd bias ----------
// Tile M=224 x N=128, K=512 in 16 kc-steps. 12768 blocks (399 tiles x 32 b), swizzled:
// groups of 16 tiles x 32 b, tile-fast (per-XCD working set ~3.5MB -> L2-resident).
// Each wave: all 14 m-tiles x 32 cols = 28 MFMA per iter; A(14336B)+B(8192B) staged via
// async global_load_lds into double buffers (no staging VGPRs, no B reg prefetch).
// Epilogue: 8 phases x 16 cols, S ping-pong (2x14592B) + ew, all inside 45056B LDS.
// acc[14][2] MUST be indexed with compile-time subscripts only (scratch-demotion trap).
__global__ __launch_bounds__(256,3) void k_main(const u16* __restrict__ TXT, const u16* __restrict__ LOC,
                                                const float* __restrict__ ewg, const float* __restrict__ vbuf,
                                                float* __restrict__ bias){
  __shared__ __align__(16) char smem[45056];
  const int tid = threadIdx.x, lane = tid & 63, wv = tid >> 6;
  const int quad = lane >> 4, l16 = lane & 15;

  // swizzle: 24 groups of (16 tiles x 32 b) + remainder (15 tiles x 32 b), tile-fast
  int id = blockIdx.x, b, tile;
  if (id < 12288){
    int g = id >> 9, r = id & 511;
    b = r >> 4; tile = (g << 4) + (r & 15);
  } else {
    int r = id - 12288;          // 0..479
    b = r / 15; tile = 384 + r % 15;
  }
  const int cn0 = tile * 128;

  const f32x4 zero = {0.f,0.f,0.f,0.f};
  f32x4 acc[14][2];
  #pragma unroll
  for (int t=0;t<14;++t){ acc[t][0]=zero; acc[t][1]=zero; }

  const char* Abase = (const char*)(LOC + (size_t)(b*16)*224*32);
  const char* Bbase = (const char*)(TXT) + (size_t)cn0*64;
  char* A0 = smem;          char* A1 = smem + 14336;
  char* B0 = smem + 28672;  char* B1 = smem + 36864;   // 8192 each, end 45056

  auto stage = [&](int kc, char* dA, char* dB){
    const char* sa = Abase + (size_t)kc*14336;
    #pragma unroll
    for (int j=0;j<4;++j){
      int ch0 = j*256 + wv*64;
      if (ch0 < 896) cp16(dA + ch0*16, sa + (size_t)(ch0 + lane)*16);
    }
    const char* sb = Bbase + (size_t)kc*CNPAD*64;
    #pragma unroll
    for (int j=0;j<2;++j){
      int ch0 = j*256 + wv*64;
      cp16(dB + ch0*16, sb + (size_t)(ch0 + lane)*16);
    }
  };

  const int aoff = l16*64 + quad*16;              // A frag base (bytes)
  const int boff = (32*wv + l16)*64 + quad*16;    // B frag base (bytes)

  stage(0, A0, B0);
  __syncthreads();

  for (int kc = 0; kc < 16; ++kc){
    const char* Ac = (kc & 1) ? A1 : A0;
    const char* Bc = (kc & 1) ? B1 : B0;
    if (kc < 15) stage(kc+1, (kc&1)?A0:A1, (kc&1)?B0:B1);
    bf16x8 bf0 = *(const bf16x8*)(Bc + boff);
    bf16x8 bf1 = *(const bf16x8*)(Bc + boff + 1024);
    #pragma unroll
    for (int t=0;t<14;++t){
      bf16x8 af = *(const bf16x8*)(Ac + aoff + t*1024);
      acc[t][0] = __builtin_amdgcn_mfma_f32_16x16x32_bf16(af, bf0, acc[t][0], 0,0,0);
      acc[t][1] = __builtin_amdgcn_mfma_f32_16x16x32_bf16(af, bf1, acc[t][1], 0,0,0);
    }
    __syncthreads();
  }

  // ---- epilogue: 8 phases x 16 cols; S ping-pong reuses staging LDS ----
  float* Sb[2] = { (float*)smem, (float*)(smem + 14592) };
  float* ewl   = (float*)(smem + 29184);   // 896 B, end 30080
  if (tid < 224) ewl[tid] = ewg[(size_t)b*224 + tid];
  // pre-write phase 0 (wave 0, group 0)
  if (wv == 0){
    #pragma unroll
    for (int t=0;t<14;++t)
      *(f32x4*)(Sb[0] + (size_t)l16*228 + 16*t + quad*4) = acc[t][0];
  }
  __syncthreads();
  float e0=0.f,e1=0.f,e2=0.f,e3=0.f;
  if (lane < 49){ const float* p = ewl + 4*lane; e0=p[0]; e1=p[1]; e2=p[2]; e3=p[3]; }

  #pragma unroll
  for (int ph=0; ph<8; ++ph){
    // writer for next phase (different S buffer than current readers)
    if (ph < 7 && wv == ((ph+1)>>1)){
      const int j2 = (ph+1)&1;
      float* D = Sb[(ph+1)&1];
      #pragma unroll
      for (int t=0;t<14;++t)
        *(f32x4*)(D + (size_t)l16*228 + 16*t + quad*4) = acc[t][j2];
    }
    const float* S = Sb[ph&1];

    #pragma unroll
    for (int i=0;i<4;++i){
      int nl = wv*4 + i;
      int cn = cn0 + ph*16 + nl;
      if (cn < 51000){
        float s0,s1,s2,s3;
        if (lane < 49){
          const float* p = S + (size_t)nl*228 + 4*lane;
          s0=p[0]; s1=p[1]; s2=p[2]; s3=p[3];
        } else { s0=s1=s2=s3=-1e30f; }

        auto cntge = [&](float t)->int{
          unsigned long long c0=__ballot(s0>=t), c1=__ballot(s1>=t);
          unsigned long long c2=__ballot(s2>=t), c3=__ballot(s3>=t);
          return __popcll(c0)+__popcll(c1)+__popcll(c2)+__popcll(c3);
        };

        // Gaussian-quantile bracket from mean/std (rank 50/196 -> z ~ 0.65)
        float su=0.f, sq=0.f;
        if (lane < 49){
          su = s0+s1+s2+s3;
          sq = fmaf(s0,s0, fmaf(s1,s1, fmaf(s2,s2, s3*s3)));
        }
        su = wsum(su); sq = wsum(sq);
        float mu = su * (1.0f/196.0f);
        float sg = sqrtf(fmaxf(sq*(1.0f/196.0f) - mu*mu, 0.0f)) + 1e-9f;
        float lo = mu + 0.15f*sg, hi = mu + 1.30f*sg;
        float thr;
        int cl = cntge(lo);
        #pragma unroll 1
        while (cl < 50){ hi = lo; lo -= sg; cl = cntge(lo); }   // widen down (rare)
        if (cl == 50) thr = lo;
        else {
          int chh = cntge(hi);
          #pragma unroll 1
          while (chh > 50){ lo = hi; hi += sg; chh = cntge(hi); } // widen up (rare)
          if (chh == 50) thr = hi;
          else {
            thr = lo;
            #pragma unroll 1
            for (int it=0; it<16; ++it){
              float tm = 0.5f*(lo+hi);
              int c = cntge(tm);
              if (c == 50){ thr = tm; break; }
              if (c > 50) lo = tm; else hi = tm;
              thr = lo;
            }
          }
        }

        float num=0.f, den=0.f;
        if (s0>=thr){ num += s0*e0; den += e0; }
        if (s1>=thr){ num += s1*e1; den += e1; }
        if (s2>=thr){ num += s2*e2; den += e2; }
        if (s3>=thr){ num += s3*e3; den += e3; }
        num = wsum(num); den = wsum(den);
        if (lane==0){
          int c = cn/51;
          atomicAdd(bias + (size_t)b*1000 + c, vbuf[cn]*(num/den));
        }
      }
    }
    __syncthreads();
  }
}

// ---------- K7: out = fp32( exp(logit_scale) * bias ) ----------
__global__ void k_out(const float* __restrict__ bias, const float* __restrict__ ls, float* __restrict__ out){
  int i = blockIdx.x*256 + threadIdx.x;
  if (i < 32000){
    float sc = expf(ls[0]);
    out[i] = sc * bias[i];
  }
}

// ---------- launch ----------
extern "C" void kernel_launch(void* const* d_in, const int* in_sizes, int n_in,
                              void* d_out, int out_size, void* d_ws, size_t ws_size,
                              hipStream_t stream) {
  const float* img = (const float*)d_in[0];
  const float* loc = (const float*)d_in[1];
  const float* txt = (const float*)d_in[2];
  const float* ls  = (const float*)d_in[3];
  char* ws = (char*)d_ws;
  // layout (total 62,112,000 B <= the 62.25 MB footprint that ran in R2-R5)
  float* imgn = (float*)(ws + 0);            //    65,536
  float* MT   = (float*)(ws + 65536);        // 2,048,000
  float* vbuf = (float*)(ws + 2113536);      //   204,032
  float* ewg  = (float*)(ws + 2317568);      //    28,672
  float* bias = (float*)(ws + 2346240);      //   128,000
  u16*   TXT  = (u16*)  (ws + 2474240);      // 52,297,728 (16 x 51072 x 32 x 2)
  u16*   LOC  = (u16*)  (ws + 54771968);     //  7,340,032
  float* invn = (float*)(ws + 54771968);     // aliases LOC head: dead before k_loc writes

  k_img <<<dim3(32),      dim3(64),  0, stream>>>(img, imgn);
  k_txt <<<dim3(CNPAD),   dim3(64),  0, stream>>>(txt, TXT, invn);
  k_mean<<<dim3(1000),    dim3(256), 0, stream>>>(txt, invn, MT);
  k_v   <<<dim3(1000),    dim3(64),  0, stream>>>(TXT, MT, vbuf);
  k_base<<<dim3(1000),    dim3(64),  0, stream>>>(imgn, MT, bias);
  k_loc <<<dim3(224,32),  dim3(64),  0, stream>>>(loc, imgn, LOC, ewg);
  k_main<<<dim3(12768),   dim3(256), 0, stream>>>(TXT, LOC, ewg, vbuf, bias);
  k_out <<<dim3(125),     dim3(256), 0, stream>>>(bias, ls, (float*)d_out);
}

// Round 7
// 1283.303 us; speedup vs baseline: 1.2734x; 1.2734x over previous
//
#include <hip/hip_runtime.h>
#include <stdint.h>

typedef __bf16  bf16x8 __attribute__((ext_vector_type(8)));
typedef float   f32x4  __attribute__((ext_vector_type(4)));
typedef unsigned short u16;

#define TEMP 5.0f

// ---------- helpers ----------
__device__ inline float wsum(float v){
  #pragma unroll
  for (int off=32; off; off>>=1) v += __shfl_xor(v, off, 64);
  return v;
}
__device__ inline float wmax(float v){
  #pragma unroll
  for (int off=32; off; off>>=1) v = fmaxf(v, __shfl_xor(v, off, 64));
  return v;
}
__device__ inline u16 f2bf(float f){               // RNE float->bf16
  unsigned u = __float_as_uint(f);
  u = u + 0x7fffu + ((u>>16)&1u);
  return (u16)(u>>16);
}
__device__ inline float bfl(unsigned u){ return __uint_as_float(u<<16); }
__device__ inline float bfh(unsigned u){ return __uint_as_float(u & 0xffff0000u); }

// async 16B global->LDS: lds dst is WAVE-UNIFORM base, HW adds lane*16
__device__ inline void cp16(void* lds_uniform, const void* g){
  __builtin_amdgcn_global_load_lds(
    (const __attribute__((address_space(1))) unsigned int*)g,
    (__attribute__((address_space(3))) unsigned int*)lds_uniform, 16, 0, 0);
}

// ---------- K0: normalize image features (32x512) ----------
__global__ void k_img(const float* __restrict__ X, float* __restrict__ imgn){
  int b = blockIdx.x, lane = threadIdx.x;
  const float* src = X + (size_t)b*512 + lane*8;
  float4 a = *(const float4*)src;
  float4 c = *(const float4*)(src+4);
  float ss = a.x*a.x+a.y*a.y+a.z*a.z+a.w*a.w + c.x*c.x+c.y*c.y+c.z*c.z+c.w*c.w;
  ss = wsum(ss);
  float inv = 1.0f/sqrtf(ss);
  float* dst = imgn + (size_t)b*512 + lane*8;
  float4 o0 = {a.x*inv,a.y*inv,a.z*inv,a.w*inv};
  float4 o1 = {c.x*inv,c.y*inv,c.z*inv,c.w*inv};
  *(float4*)dst = o0; *(float4*)(dst+4) = o1;
}

// ---------- K1: normalize txt; bf16 K-chunked TXT[kc][cn(51008)][32]; invn[n*1000+c] ----------
__global__ void k_txt(const float* __restrict__ X, u16* __restrict__ TXT, float* __restrict__ invn){
  int cn = blockIdx.x, lane = threadIdx.x;
  int kc = lane>>2, kk8 = (lane&3)*8;
  size_t dstE = ((size_t)kc*51008 + cn)*32 + kk8;
  if (cn >= 51000){
    uint4 z = {0,0,0,0};
    *(uint4*)(TXT + dstE) = z;
    return;
  }
  int c = cn/51, n = cn - c*51;
  const float* src = X + ((size_t)n*1000 + c)*512 + lane*8;
  float4 a = *(const float4*)src;
  float4 d = *(const float4*)(src+4);
  float ss = a.x*a.x+a.y*a.y+a.z*a.z+a.w*a.w + d.x*d.x+d.y*d.y+d.z*d.z+d.w*d.w;
  ss = wsum(ss);
  float inv = 1.0f/sqrtf(ss);
  u16 h0=f2bf(a.x*inv),h1=f2bf(a.y*inv),h2=f2bf(a.z*inv),h3=f2bf(a.w*inv);
  u16 h4=f2bf(d.x*inv),h5=f2bf(d.y*inv),h6=f2bf(d.z*inv),h7=f2bf(d.w*inv);
  uint4 o;
  o.x = (unsigned)h0 | ((unsigned)h1<<16);
  o.y = (unsigned)h2 | ((unsigned)h3<<16);
  o.z = (unsigned)h4 | ((unsigned)h5<<16);
  o.w = (unsigned)h6 | ((unsigned)h7<<16);
  *(uint4*)(TXT + dstE) = o;
  if (lane==0) invn[(size_t)n*1000 + c] = inv;
}

// ---------- K2: mean_txt[c] = l2norm( sum_n txt_n[c] ) ----------
__global__ void k_mean(const float* __restrict__ X, const float* __restrict__ invn, float* __restrict__ MT){
  int c = blockIdx.x, tid = threadIdx.x, lane = tid&63, wv = tid>>6;
  __shared__ float sinv[51];
  __shared__ float red[4];
  if (tid < 51) sinv[tid] = invn[(size_t)tid*1000 + c];
  __syncthreads();
  int d0 = tid*2;
  float sx=0.f, sy=0.f;
  for (int n=0;n<51;++n){
    const float2 x = *(const float2*)(X + ((size_t)n*1000 + c)*512 + d0);
    float iv = sinv[n];
    sx += x.x*iv; sy += x.y*iv;
  }
  float ss = sx*sx + sy*sy;
  ss = wsum(ss);
  if (lane==0) red[wv] = ss;
  __syncthreads();
  float tot = red[0]+red[1]+red[2]+red[3];
  float inv = 1.0f/sqrtf(tot);
  float2 o = {sx*inv, sy*inv};
  *(float2*)(MT + (size_t)c*512 + d0) = o;
}

// ---------- K3: v[c,n] = softmax_n( TEMP * mean_txt[c].txt[n,c] ) ----------
__global__ void k_v(const u16* __restrict__ TXT, const float* __restrict__ MT, float* __restrict__ vbuf){
  int c = blockIdx.x, lane = threadIdx.x;
  __shared__ float lg[51];
  const float* mp = MT + (size_t)c*512 + lane*8;
  float4 m0 = *(const float4*)mp;
  float4 m1 = *(const float4*)(mp+4);
  int kc = lane>>2, kk8 = (lane&3)*8;
  for (int n=0;n<51;++n){
    size_t e = ((size_t)kc*51008 + (size_t)(c*51+n))*32 + kk8;
    uint4 q = *(const uint4*)(TXT + e);
    float d = bfl(q.x)*m0.x + bfh(q.x)*m0.y + bfl(q.y)*m0.z + bfh(q.y)*m0.w
            + bfl(q.z)*m1.x + bfh(q.z)*m1.y + bfl(q.w)*m1.z + bfh(q.w)*m1.w;
    d = wsum(d);
    if (lane==0) lg[n] = d;
  }
  __syncthreads();
  float val = (lane<51) ? lg[lane] : -1e30f;
  float mx = wmax(val);
  float e = (lane<51) ? expf(TEMP*(val-mx)) : 0.f;
  float s = wsum(e);
  if (lane<51) vbuf[(size_t)c*51 + lane] = e/s;
}

// ---------- K4: bias[b,c] = base_logits ----------
__global__ void k_base(const float* __restrict__ imgn, const float* __restrict__ MT, float* __restrict__ bias){
  int c = blockIdx.x, lane = threadIdx.x;
  const float* mp = MT + (size_t)c*512 + lane*8;
  float4 m0 = *(const float4*)mp;
  float4 m1 = *(const float4*)(mp+4);
  for (int b=0;b<32;++b){
    const float* ip = imgn + (size_t)b*512 + lane*8;
    float4 i0 = *(const float4*)ip;
    float4 i1 = *(const float4*)(ip+4);
    float d = i0.x*m0.x+i0.y*m0.y+i0.z*m0.z+i0.w*m0.w
            + i1.x*m1.x+i1.y*m1.y+i1.z*m1.z+i1.w*m1.w;
    d = wsum(d);
    if (lane==0) bias[(size_t)b*1000 + c] = d;
  }
}

// ---------- K5: normalize loc; LOC[b][kc][m(224)][32] bf16; ew[b,m] ----------
__global__ void k_loc(const float* __restrict__ L, const float* __restrict__ imgn,
                      u16* __restrict__ LOC, float* __restrict__ ewg){
  int m = blockIdx.x, b = blockIdx.y, lane = threadIdx.x;
  size_t dstE = ((size_t)(b*16 + (lane>>2))*224 + m)*32 + (lane&3)*8;
  if (m >= 196){
    uint4 z = {0,0,0,0};
    *(uint4*)(LOC + dstE) = z;
    if (lane==0) ewg[(size_t)b*224 + m] = 0.f;
    return;
  }
  const float* src = L + ((size_t)b*196 + m)*512 + lane*8;
  float4 a = *(const float4*)src;
  float4 d = *(const float4*)(src+4);
  const float* ip = imgn + (size_t)b*512 + lane*8;
  float4 i0 = *(const float4*)ip;
  float4 i1 = *(const float4*)(ip+4);
  float ss = a.x*a.x+a.y*a.y+a.z*a.z+a.w*a.w + d.x*d.x+d.y*d.y+d.z*d.z+d.w*d.w;
  float ws = a.x*i0.x+a.y*i0.y+a.z*i0.z+a.w*i0.w + d.x*i1.x+d.y*i1.y+d.z*i1.z+d.w*i1.w;
  ss = wsum(ss); ws = wsum(ws);
  float inv = 1.0f/sqrtf(ss);
  u16 h0=f2bf(a.x*inv),h1=f2bf(a.y*inv),h2=f2bf(a.z*inv),h3=f2bf(a.w*inv);
  u16 h4=f2bf(d.x*inv),h5=f2bf(d.y*inv),h6=f2bf(d.z*inv),h7=f2bf(d.w*inv);
  uint4 o;
  o.x = (unsigned)h0 | ((unsigned)h1<<16);
  o.y = (unsigned)h2 | ((unsigned)h3<<16);
  o.z = (unsigned)h4 | ((unsigned)h5<<16);
  o.w = (unsigned)h6 | ((unsigned)h7<<16);
  *(uint4*)(LOC + dstE) = o;
  if (lane==0) ewg[(size_t)b*224 + m] = expf(TEMP * ws * inv);
}

struct B2 { bf16x8 x, y; };

// ---------- K6: fused GEMM (MFMA bf16) + top-50 + weighted sum -> atomicAdd bias ----------
// R5 structure (best so far): tile M=224 x N=64, K=512 / 16 steps; A via async
// global_load_lds dbuf (28672 B LDS), B reg-prefetch; group swizzle 32 tiles x 32 b.
// R7 changes: __launch_bounds__(256,5) (LDS admits 5 blocks/CU; VGPR ~56 << 102 cap)
// and a BRANCH-FREE selection: bracket [2mu-max, max+eps] (provably valid), 13
// straight-line bisection steps (cndmask, no early-exit), resolution ~span/8192.
// acc[] must use compile-time indices only (scratch-demotion trap, R4).
__global__ __launch_bounds__(256,5) void k_main(const u16* __restrict__ TXT, const u16* __restrict__ LOC,
                                                const float* __restrict__ ewg, const float* __restrict__ vbuf,
                                                float* __restrict__ bias){
  __shared__ __align__(16) char smem[28672];
  const int tid = threadIdx.x, lane = tid & 63, wv = tid >> 6;
  const int quad = lane >> 4, l16 = lane & 15;
  const int ms = wv >> 1, ns = wv & 1;

  // group swizzle: groups of 32 cn-tiles x 32 b; last group 29 x 32
  int id = blockIdx.x, b, cnt_;
  if (id < 24576){
    int g = id >> 10, r = id & 1023;
    b = r >> 5;  cnt_ = (g << 5) + (r & 31);
  } else {
    int r = id - 24576;
    b = r / 29;  cnt_ = 768 + r % 29;
  }
  const int cn0 = cnt_ * 64;

  const f32x4 zero = {0.f,0.f,0.f,0.f};
  f32x4 acc[7][2];
  #pragma unroll
  for (int t=0;t<7;++t){ acc[t][0]=zero; acc[t][1]=zero; }

  const u16* Abase = LOC + (size_t)(b*16)*224*32;
  char* Albd0 = smem;
  char* Albd1 = smem + 14336;

  auto stageA = [&](int kc, char* dst){
    const char* src = (const char*)(Abase + (size_t)kc*224*32);
    #pragma unroll
    for (int j=0;j<4;++j){
      int ch0 = j*256 + wv*64;                 // wave-uniform chunk base
      if (ch0 < 896)
        cp16(dst + (size_t)ch0*16, src + (size_t)(ch0 + lane)*16);
    }
  };
  auto loadB = [&](int kc)->B2{
    B2 r;
    size_t e = ((size_t)kc*51008 + (size_t)(cn0 + 32*ns + l16))*32 + quad*8;
    r.x = *(const bf16x8*)(TXT + e);
    r.y = *(const bf16x8*)(TXT + e + 16*32);
    return r;
  };
  auto domfma = [&](const char* Ab, B2 bb){
    #pragma unroll
    for (int t=0;t<7;++t){
      bf16x8 af = *(const bf16x8*)(Ab + (size_t)((112*ms + 16*t + l16)*64 + quad*16));
      acc[t][0] = __builtin_amdgcn_mfma_f32_16x16x32_bf16(af, bb.x, acc[t][0], 0,0,0);
      acc[t][1] = __builtin_amdgcn_mfma_f32_16x16x32_bf16(af, bb.y, acc[t][1], 0,0,0);
    }
  };

  stageA(0, Albd0);
  B2 bcur = loadB(0);
  __syncthreads();

  for (int kc = 0; kc < 16; ++kc){
    char* cur = (kc & 1) ? Albd1 : Albd0;
    char* nxt = (kc & 1) ? Albd0 : Albd1;
    B2 bnext;
    if (kc < 15){
      stageA(kc+1, nxt);
      bnext = loadB(kc+1);
    }
    domfma(cur, bcur);
    bcur = bnext;
    __syncthreads();
  }

  // ---- epilogue: 4 phases x 16 columns; S[16][228] + ew reuse staging LDS ----
  float* S   = (float*)smem;             // 16*228*4 = 14592 B
  float* ewl = (float*)(smem + 14592);   // 224*4 = 896 B
  if (tid < 224) ewl[tid] = ewg[(size_t)b*224 + tid];
  __syncthreads();
  float e0=0.f,e1=0.f,e2=0.f,e3=0.f;
  if (lane < 49){ const float* p = ewl + 4*lane; e0=p[0]; e1=p[1]; e2=p[2]; e3=p[3]; }

  #pragma unroll
  for (int ph=0; ph<4; ++ph){            // MUST be unrolled: acc index j2 = ph&1
    if (ns == (ph>>1)){
      const int j2 = ph & 1;
      #pragma unroll
      for (int t=0;t<7;++t){
        int m0 = 112*ms + 16*t + quad*4;
        *(f32x4*)(S + (size_t)l16*228 + m0) = acc[t][j2];
      }
    }
    __syncthreads();

    #pragma unroll
    for (int i=0;i<4;++i){
      int nl = wv*4 + i;
      int cn = cn0 + ph*16 + nl;
      if (cn < 51000){
        float s0,s1,s2,s3, su;
        if (lane < 49){
          const float* p = S + (size_t)nl*228 + 4*lane;
          s0=p[0]; s1=p[1]; s2=p[2]; s3=p[3];
          su = s0+s1+s2+s3;
        } else { s0=s1=s2=s3=-1e30f; su=0.f; }

        // bracket [2*mu - max, max + eps]: count(lo)>=50 (near-symmetric dist,
        // mirror of max is deep left tail), count(hi)=0 < 50.
        float vmax = wmax(fmaxf(fmaxf(s0,s1),fmaxf(s2,s3)));
        float mu   = wsum(su) * (1.0f/196.0f);
        float lo = mu + mu - vmax, hi = vmax + 1e-6f;

        // 13 branch-free bisection steps: invariant cnt(lo)>=50 > cnt(hi)
        #pragma unroll
        for (int it=0; it<13; ++it){
          float tm = 0.5f*(lo+hi);
          int cnt = __popcll(__ballot(s0>=tm)) + __popcll(__ballot(s1>=tm))
                  + __popcll(__ballot(s2>=tm)) + __popcll(__ballot(s3>=tm));
          bool ge = (cnt >= 50);
          lo = ge ? tm : lo;
          hi = ge ? hi : tm;
        }
        float thr = lo;

        float num=0.f, den=0.f;
        if (s0>=thr){ num += s0*e0; den += e0; }
        if (s1>=thr){ num += s1*e1; den += e1; }
        if (s2>=thr){ num += s2*e2; den += e2; }
        if (s3>=thr){ num += s3*e3; den += e3; }
        num = wsum(num); den = wsum(den);
        if (lane==0){
          int c = cn/51;
          atomicAdd(bias + (size_t)b*1000 + c, vbuf[cn]*(num/den));
        }
      }
    }
    __syncthreads();
  }
}

// ---------- K7: out = fp32( exp(logit_scale) * bias ) ----------
__global__ void k_out(const float* __restrict__ bias, const float* __restrict__ ls, float* __restrict__ out){
  int i = blockIdx.x*256 + threadIdx.x;
  if (i < 32000){
    float sc = expf(ls[0]);
    out[i] = sc * bias[i];
  }
}

// ---------- launch ----------
extern "C" void kernel_launch(void* const* d_in, const int* in_sizes, int n_in,
                              void* d_out, int out_size, void* d_ws, size_t ws_size,
                              hipStream_t stream) {
  const float* img = (const float*)d_in[0];
  const float* loc = (const float*)d_in[1];
  const float* txt = (const float*)d_in[2];
  const float* ls  = (const float*)d_in[3];
  char* ws = (char*)d_ws;
  float* imgn = (float*)(ws + 0);            //  65536
  float* MT   = (float*)(ws + 65536);        //  2048000
  float* invn = (float*)(ws + 2113536);      //  204032
  float* vbuf = (float*)(ws + 2317568);      //  204032
  float* ewg  = (float*)(ws + 2521600);      //  28672
  float* bias = (float*)(ws + 2550272);      //  128000
  u16*   TXT  = (u16*)  (ws + 2678272);      //  52232192
  u16*   LOC  = (u16*)  (ws + 54910464);     //  7340032

  k_img <<<dim3(32),      dim3(64),  0, stream>>>(img, imgn);
  k_txt <<<dim3(51008),   dim3(64),  0, stream>>>(txt, TXT, invn);
  k_mean<<<dim3(1000),    dim3(256), 0, stream>>>(txt, invn, MT);
  k_v   <<<dim3(1000),    dim3(64),  0, stream>>>(TXT, MT, vbuf);
  k_base<<<dim3(1000),    dim3(64),  0, stream>>>(imgn, MT, bias);
  k_loc <<<dim3(224,32),  dim3(64),  0, stream>>>(loc, imgn, LOC, ewg);
  k_main<<<dim3(25504),   dim3(256), 0, stream>>>(TXT, LOC, ewg, vbuf, bias);
  k_out <<<dim3(125),     dim3(256), 0, stream>>>(bias, ls, (float*)d_out);
}

// Round 8
// 1240.116 us; speedup vs baseline: 1.3177x; 1.0348x over previous
//
#include <hip/hip_runtime.h>
#include <stdint.h>

typedef __bf16  bf16x8 __attribute__((ext_vector_type(8)));
typedef float   f32x4  __attribute__((ext_vector_type(4)));
typedef unsigned short u16;

#define TEMP 5.0f

// ---------- helpers ----------
__device__ inline float wsum(float v){
  #pragma unroll
  for (int off=32; off; off>>=1) v += __shfl_xor(v, off, 64);
  return v;
}
__device__ inline float wmax(float v){
  #pragma unroll
  for (int off=32; off; off>>=1) v = fmaxf(v, __shfl_xor(v, off, 64));
  return v;
}
__device__ inline u16 f2bf(float f){               // RNE float->bf16
  unsigned u = __float_as_uint(f);
  u = u + 0x7fffu + ((u>>16)&1u);
  return (u16)(u>>16);
}
__device__ inline float bfl(unsigned u){ return __uint_as_float(u<<16); }
__device__ inline float bfh(unsigned u){ return __uint_as_float(u & 0xffff0000u); }

// async 16B global->LDS: lds dst is WAVE-UNIFORM base, HW adds lane*16
__device__ inline void cp16(void* lds_uniform, const void* g){
  __builtin_amdgcn_global_load_lds(
    (const __attribute__((address_space(1))) unsigned int*)g,
    (__attribute__((address_space(3))) unsigned int*)lds_uniform, 16, 0, 0);
}

// ---------- K0: normalize image features (32x512) ----------
__global__ void k_img(const float* __restrict__ X, float* __restrict__ imgn){
  int b = blockIdx.x, lane = threadIdx.x;
  const float* src = X + (size_t)b*512 + lane*8;
  float4 a = *(const float4*)src;
  float4 c = *(const float4*)(src+4);
  float ss = a.x*a.x+a.y*a.y+a.z*a.z+a.w*a.w + c.x*c.x+c.y*c.y+c.z*c.z+c.w*c.w;
  ss = wsum(ss);
  float inv = 1.0f/sqrtf(ss);
  float* dst = imgn + (size_t)b*512 + lane*8;
  float4 o0 = {a.x*inv,a.y*inv,a.z*inv,a.w*inv};
  float4 o1 = {c.x*inv,c.y*inv,c.z*inv,c.w*inv};
  *(float4*)dst = o0; *(float4*)(dst+4) = o1;
}

// ---------- K1: normalize txt; bf16 K-chunked TXT[kc][cn(51008)][32]; invn[n*1000+c] ----------
__global__ void k_txt(const float* __restrict__ X, u16* __restrict__ TXT, float* __restrict__ invn){
  int cn = blockIdx.x, lane = threadIdx.x;
  int kc = lane>>2, kk8 = (lane&3)*8;
  size_t dstE = ((size_t)kc*51008 + cn)*32 + kk8;
  if (cn >= 51000){
    uint4 z = {0,0,0,0};
    *(uint4*)(TXT + dstE) = z;
    return;
  }
  int c = cn/51, n = cn - c*51;
  const float* src = X + ((size_t)n*1000 + c)*512 + lane*8;
  float4 a = *(const float4*)src;
  float4 d = *(const float4*)(src+4);
  float ss = a.x*a.x+a.y*a.y+a.z*a.z+a.w*a.w + d.x*d.x+d.y*d.y+d.z*d.z+d.w*d.w;
  ss = wsum(ss);
  float inv = 1.0f/sqrtf(ss);
  u16 h0=f2bf(a.x*inv),h1=f2bf(a.y*inv),h2=f2bf(a.z*inv),h3=f2bf(a.w*inv);
  u16 h4=f2bf(d.x*inv),h5=f2bf(d.y*inv),h6=f2bf(d.z*inv),h7=f2bf(d.w*inv);
  uint4 o;
  o.x = (unsigned)h0 | ((unsigned)h1<<16);
  o.y = (unsigned)h2 | ((unsigned)h3<<16);
  o.z = (unsigned)h4 | ((unsigned)h5<<16);
  o.w = (unsigned)h6 | ((unsigned)h7<<16);
  *(uint4*)(TXT + dstE) = o;
  if (lane==0) invn[(size_t)n*1000 + c] = inv;
}

// ---------- K2: mean_txt[c] = l2norm( sum_n txt_n[c] ) ----------
__global__ void k_mean(const float* __restrict__ X, const float* __restrict__ invn, float* __restrict__ MT){
  int c = blockIdx.x, tid = threadIdx.x, lane = tid&63, wv = tid>>6;
  __shared__ float sinv[51];
  __shared__ float red[4];
  if (tid < 51) sinv[tid] = invn[(size_t)tid*1000 + c];
  __syncthreads();
  int d0 = tid*2;
  float sx=0.f, sy=0.f;
  for (int n=0;n<51;++n){
    const float2 x = *(const float2*)(X + ((size_t)n*1000 + c)*512 + d0);
    float iv = sinv[n];
    sx += x.x*iv; sy += x.y*iv;
  }
  float ss = sx*sx + sy*sy;
  ss = wsum(ss);
  if (lane==0) red[wv] = ss;
  __syncthreads();
  float tot = red[0]+red[1]+red[2]+red[3];
  float inv = 1.0f/sqrtf(tot);
  float2 o = {sx*inv, sy*inv};
  *(float2*)(MT + (size_t)c*512 + d0) = o;
}

// ---------- K3: v[c,n] = softmax_n( TEMP * mean_txt[c].txt[n,c] ) ----------
__global__ void k_v(const u16* __restrict__ TXT, const float* __restrict__ MT, float* __restrict__ vbuf){
  int c = blockIdx.x, lane = threadIdx.x;
  __shared__ float lg[51];
  const float* mp = MT + (size_t)c*512 + lane*8;
  float4 m0 = *(const float4*)mp;
  float4 m1 = *(const float4*)(mp+4);
  int kc = lane>>2, kk8 = (lane&3)*8;
  for (int n=0;n<51;++n){
    size_t e = ((size_t)kc*51008 + (size_t)(c*51+n))*32 + kk8;
    uint4 q = *(const uint4*)(TXT + e);
    float d = bfl(q.x)*m0.x + bfh(q.x)*m0.y + bfl(q.y)*m0.z + bfh(q.y)*m0.w
            + bfl(q.z)*m1.x + bfh(q.z)*m1.y + bfl(q.w)*m1.z + bfh(q.w)*m1.w;
    d = wsum(d);
    if (lane==0) lg[n] = d;
  }
  __syncthreads();
  float val = (lane<51) ? lg[lane] : -1e30f;
  float mx = wmax(val);
  float e = (lane<51) ? expf(TEMP*(val-mx)) : 0.f;
  float s = wsum(e);
  if (lane<51) vbuf[(size_t)c*51 + lane] = e/s;
}

// ---------- K4: bias[b,c] = base_logits ----------
__global__ void k_base(const float* __restrict__ imgn, const float* __restrict__ MT, float* __restrict__ bias){
  int c = blockIdx.x, lane = threadIdx.x;
  const float* mp = MT + (size_t)c*512 + lane*8;
  float4 m0 = *(const float4*)mp;
  float4 m1 = *(const float4*)(mp+4);
  for (int b=0;b<32;++b){
    const float* ip = imgn + (size_t)b*512 + lane*8;
    float4 i0 = *(const float4*)ip;
    float4 i1 = *(const float4*)(ip+4);
    float d = i0.x*m0.x+i0.y*m0.y+i0.z*m0.z+i0.w*m0.w
            + i1.x*m1.x+i1.y*m1.y+i1.z*m1.z+i1.w*m1.w;
    d = wsum(d);
    if (lane==0) bias[(size_t)b*1000 + c] = d;
  }
}

// ---------- K5: normalize loc; LOC[b][kc][m(224)][32] bf16; ew[b,m] (0 for m>=196) ----------
__global__ void k_loc(const float* __restrict__ L, const float* __restrict__ imgn,
                      u16* __restrict__ LOC, float* __restrict__ ewg){
  int m = blockIdx.x, b = blockIdx.y, lane = threadIdx.x;
  size_t dstE = ((size_t)(b*16 + (lane>>2))*224 + m)*32 + (lane&3)*8;
  if (m >= 196){
    uint4 z = {0,0,0,0};
    *(uint4*)(LOC + dstE) = z;
    if (lane==0) ewg[(size_t)b*224 + m] = 0.f;
    return;
  }
  const float* src = L + ((size_t)b*196 + m)*512 + lane*8;
  float4 a = *(const float4*)src;
  float4 d = *(const float4*)(src+4);
  const float* ip = imgn + (size_t)b*512 + lane*8;
  float4 i0 = *(const float4*)ip;
  float4 i1 = *(const float4*)(ip+4);
  float ss = a.x*a.x+a.y*a.y+a.z*a.z+a.w*a.w + d.x*d.x+d.y*d.y+d.z*d.z+d.w*d.w;
  float ws = a.x*i0.x+a.y*i0.y+a.z*i0.z+a.w*i0.w + d.x*i1.x+d.y*i1.y+d.z*i1.z+d.w*i1.w;
  ss = wsum(ss); ws = wsum(ws);
  float inv = 1.0f/sqrtf(ss);
  u16 h0=f2bf(a.x*inv),h1=f2bf(a.y*inv),h2=f2bf(a.z*inv),h3=f2bf(a.w*inv);
  u16 h4=f2bf(d.x*inv),h5=f2bf(d.y*inv),h6=f2bf(d.z*inv),h7=f2bf(d.w*inv);
  uint4 o;
  o.x = (unsigned)h0 | ((unsigned)h1<<16);
  o.y = (unsigned)h2 | ((unsigned)h3<<16);
  o.z = (unsigned)h4 | ((unsigned)h5<<16);
  o.w = (unsigned)h6 | ((unsigned)h7<<16);
  *(uint4*)(LOC + dstE) = o;
  if (lane==0) ewg[(size_t)b*224 + m] = expf(TEMP * ws * inv);
}

struct B2 { bf16x8 x, y; };

// ---------- K6: fused GEMM (MFMA bf16) + in-register top-50 + weighted sum ----------
// K-loop identical to R7 (tile M=224 x N=64, async global_load_lds A dbuf, B reg prefetch,
// group swizzle 32 tiles x 32 b). NEW epilogue: no S-matrix round-trip. MFMA C-layout
// puts column n in 4 lanes (l16=n&15, quad=0..3) x 28 regs; wave (ms,ns) targets cols
// j2=ms and only exchanges the complementary m-half with its partner wave via a
// bank-conflict-free LDS region (stride 116 floats). Top-50 bisection runs fully in
// registers, 16 columns per wave in parallel; counts via 2-step quad shuffle.
// Pad rows m>=196 live in half-1 t=5(quad!=0)/t=6 slots -> masked to -3e38; bracket
// uses t=0..4 only (160 real values: cnt(lo)>=160, cnt(hi)<=36 -> valid bounds).
// acc[] compile-time indices only (scratch-demotion trap).
__global__ __launch_bounds__(256,4) void k_main(const u16* __restrict__ TXT, const u16* __restrict__ LOC,
                                                const float* __restrict__ ewg, const float* __restrict__ vbuf,
                                                float* __restrict__ bias){
  __shared__ __align__(16) char smem[30592];   // A dbuf 28672 | exchange 4x7424=29696 | ewl 896
  const int tid = threadIdx.x, lane = tid & 63, wv = tid >> 6;
  const int quad = lane >> 4, l16 = lane & 15;
  const int ms = wv >> 1, ns = wv & 1;

  // group swizzle: groups of 32 cn-tiles x 32 b; last group 29 x 32
  int id = blockIdx.x, b, cnt_;
  if (id < 24576){
    int g = id >> 10, r = id & 1023;
    b = r >> 5;  cnt_ = (g << 5) + (r & 31);
  } else {
    int r = id - 24576;
    b = r / 29;  cnt_ = 768 + r % 29;
  }
  const int cn0 = cnt_ * 64;

  // stage ew early (region disjoint from A dbuf; read only after final K barrier)
  float* ewl = (float*)(smem + 29696);
  if (tid < 224) ewl[tid] = ewg[(size_t)b*224 + tid];

  const f32x4 zero = {0.f,0.f,0.f,0.f};
  f32x4 acc[7][2];
  #pragma unroll
  for (int t=0;t<7;++t){ acc[t][0]=zero; acc[t][1]=zero; }

  const u16* Abase = LOC + (size_t)(b*16)*224*32;
  char* Albd0 = smem;
  char* Albd1 = smem + 14336;

  auto stageA = [&](int kc, char* dst){
    const char* src = (const char*)(Abase + (size_t)kc*224*32);
    #pragma unroll
    for (int j=0;j<4;++j){
      int ch0 = j*256 + wv*64;                 // wave-uniform chunk base
      if (ch0 < 896)
        cp16(dst + (size_t)ch0*16, src + (size_t)(ch0 + lane)*16);
    }
  };
  auto loadB = [&](int kc)->B2{
    B2 r;
    size_t e = ((size_t)kc*51008 + (size_t)(cn0 + 32*ns + l16))*32 + quad*8;
    r.x = *(const bf16x8*)(TXT + e);
    r.y = *(const bf16x8*)(TXT + e + 16*32);
    return r;
  };
  auto domfma = [&](const char* Ab, B2 bb){
    #pragma unroll
    for (int t=0;t<7;++t){
      bf16x8 af = *(const bf16x8*)(Ab + (size_t)((112*ms + 16*t + l16)*64 + quad*16));
      acc[t][0] = __builtin_amdgcn_mfma_f32_16x16x32_bf16(af, bb.x, acc[t][0], 0,0,0);
      acc[t][1] = __builtin_amdgcn_mfma_f32_16x16x32_bf16(af, bb.y, acc[t][1], 0,0,0);
    }
  };

  stageA(0, Albd0);
  B2 bcur = loadB(0);
  __syncthreads();

  for (int kc = 0; kc < 16; ++kc){
    char* cur = (kc & 1) ? Albd1 : Albd0;
    char* nxt = (kc & 1) ? Albd0 : Albd1;
    B2 bnext;
    if (kc < 15){
      stageA(kc+1, nxt);
      bnext = loadB(kc+1);
    }
    domfma(cur, bcur);
    bcur = bnext;
    __syncthreads();
  }

  // ---- epilogue: exchange complementary m-half, then in-register selection ----
  // region(ns,j2) layout: [col l16][m-local 112+pad4] floats, stride 116 (2-way banks = free)
  {
    char* wr = smem + (size_t)(((ns<<1)|(ms^1))*7424) + l16*464;
    if (ms == 0){
      #pragma unroll
      for (int t=0;t<7;++t) *(f32x4*)(wr + (16*t+4*quad)*4) = acc[t][1];
    } else {
      #pragma unroll
      for (int t=0;t<7;++t) *(f32x4*)(wr + (16*t+4*quad)*4) = acc[t][0];
    }
  }
  __syncthreads();

  f32x4 own[7], oth[7];
  {
    const char* rd = smem + (size_t)(((ns<<1)|ms)*7424) + l16*464;
    #pragma unroll
    for (int t=0;t<7;++t) oth[t] = *(const f32x4*)(rd + (16*t+4*quad)*4);
    if (ms == 0){
      #pragma unroll
      for (int t=0;t<7;++t) own[t] = acc[t][0];
    } else {
      #pragma unroll
      for (int t=0;t<7;++t) own[t] = acc[t][1];
    }
  }
  // mask pad slots (m>=196) in whichever array holds m-half-1
  const float NEGF = -3.0e38f;
  {
    bool q0 = (quad == 0);
    if (ms == 1){
      #pragma unroll
      for (int r=0;r<4;++r){ own[5][r] = q0 ? own[5][r] : NEGF; own[6][r] = NEGF; }
    } else {
      #pragma unroll
      for (int r=0;r<4;++r){ oth[5][r] = q0 ? oth[5][r] : NEGF; oth[6][r] = NEGF; }
    }
  }

  // bracket from t=0..4 (all real): cnt(lo)>=160>=50, cnt(hi)<=36<50
  float mn = own[0][0], mx = own[0][0];
  #pragma unroll
  for (int t=0;t<5;++t){
    #pragma unroll
    for (int r=0;r<4;++r){
      mn = fminf(mn, fminf(own[t][r], oth[t][r]));
      mx = fmaxf(mx, fmaxf(own[t][r], oth[t][r]));
    }
  }
  mn = fminf(mn, __shfl_xor(mn,16,64)); mn = fminf(mn, __shfl_xor(mn,32,64));
  mx = fmaxf(mx, __shfl_xor(mx,16,64)); mx = fmaxf(mx, __shfl_xor(mx,32,64));
  float lo = mn - 1e-6f, hi = mx + 1e-6f;

  for (int it=0; it<13; ++it){
    float tm = 0.5f*(lo+hi);
    int c = 0;
    #pragma unroll
    for (int t=0;t<7;++t){
      #pragma unroll
      for (int r=0;r<4;++r){
        c += (own[t][r] >= tm) ? 1 : 0;
        c += (oth[t][r] >= tm) ? 1 : 0;
      }
    }
    c += __shfl_xor(c, 16, 64);
    c += __shfl_xor(c, 32, 64);
    bool ge = (c >= 50);
    lo = ge ? tm : lo;
    hi = ge ? hi : tm;
  }
  const float thr = lo;

  float num = 0.f, den = 0.f;
  #pragma unroll
  for (int t=0;t<7;++t){
    f32x4 eA = *(const f32x4*)(ewl + 112*ms     + 16*t + 4*quad);
    f32x4 eB = *(const f32x4*)(ewl + 112*(ms^1) + 16*t + 4*quad);
    #pragma unroll
    for (int r=0;r<4;++r){
      if (own[t][r] >= thr){ num = fmaf(own[t][r], eA[r], num); den += eA[r]; }
      if (oth[t][r] >= thr){ num = fmaf(oth[t][r], eB[r], num); den += eB[r]; }
    }
  }
  num += __shfl_xor(num,16,64); num += __shfl_xor(num,32,64);
  den += __shfl_xor(den,16,64); den += __shfl_xor(den,32,64);

  int cn = cn0 + 32*ns + 16*ms + l16;
  if (quad == 0 && cn < 51000){
    int c = cn/51;
    atomicAdd(bias + (size_t)b*1000 + c, vbuf[cn]*(num/den));
  }
}

// ---------- K7: out = fp32( exp(logit_scale) * bias ) ----------
__global__ void k_out(const float* __restrict__ bias, const float* __restrict__ ls, float* __restrict__ out){
  int i = blockIdx.x*256 + threadIdx.x;
  if (i < 32000){
    float sc = expf(ls[0]);
    out[i] = sc * bias[i];
  }
}

// ---------- launch ----------
extern "C" void kernel_launch(void* const* d_in, const int* in_sizes, int n_in,
                              void* d_out, int out_size, void* d_ws, size_t ws_size,
                              hipStream_t stream) {
  const float* img = (const float*)d_in[0];
  const float* loc = (const float*)d_in[1];
  const float* txt = (const float*)d_in[2];
  const float* ls  = (const float*)d_in[3];
  char* ws = (char*)d_ws;
  float* imgn = (float*)(ws + 0);            //  65536
  float* MT   = (float*)(ws + 65536);        //  2048000
  float* invn = (float*)(ws + 2113536);      //  204032
  float* vbuf = (float*)(ws + 2317568);      //  204032
  float* ewg  = (float*)(ws + 2521600);      //  28672
  float* bias = (float*)(ws + 2550272);      //  128000
  u16*   TXT  = (u16*)  (ws + 2678272);      //  52232192
  u16*   LOC  = (u16*)  (ws + 54910464);     //  7340032

  k_img <<<dim3(32),      dim3(64),  0, stream>>>(img, imgn);
  k_txt <<<dim3(51008),   dim3(64),  0, stream>>>(txt, TXT, invn);
  k_mean<<<dim3(1000),    dim3(256), 0, stream>>>(txt, invn, MT);
  k_v   <<<dim3(1000),    dim3(64),  0, stream>>>(TXT, MT, vbuf);
  k_base<<<dim3(1000),    dim3(64),  0, stream>>>(imgn, MT, bias);
  k_loc <<<dim3(224,32),  dim3(64),  0, stream>>>(loc, imgn, LOC, ewg);
  k_main<<<dim3(25504),   dim3(256), 0, stream>>>(TXT, LOC, ewg, vbuf, bias);
  k_out <<<dim3(125),     dim3(256), 0, stream>>>(bias, ls, (float*)d_out);
}